// Round 1
// baseline (1146.297 us; speedup 1.0000x reference)
//
#include <hip/hip_runtime.h>

// GCNConv forward on MI355X.
// out[t] = relu( dinv[t] * ( y[t] + sum_{(s,t) in E} y[s] ) + b ),
// where y[n] = dinv[n] * (x @ W)[n], dinv = rsqrt(1 + indegree).
//
// Buffers: d_ws = [ deg/dinv : N floats | acc : N*H floats ]
//          d_out holds y after GEMM, then finalized in place.

#define HDIM 128
#define FDIM 128

__global__ __launch_bounds__(256) void k_init_deg(float* __restrict__ deg, int n) {
    int i = blockIdx.x * blockDim.x + threadIdx.x;
    if (i < n) deg[i] = 1.0f;  // self-loop
}

__global__ __launch_bounds__(256) void k_count_deg(const int* __restrict__ dst,
                                                   float* __restrict__ deg, int e) {
    int i = blockIdx.x * blockDim.x + threadIdx.x;
    if (i < e) atomicAdd(&deg[dst[i]], 1.0f);
}

__global__ __launch_bounds__(256) void k_rsqrt(float* __restrict__ deg, int n) {
    int i = blockIdx.x * blockDim.x + threadIdx.x;
    if (i < n) deg[i] = rsqrtf(deg[i]);
}

// y[row][h] = dinv[row] * sum_k x[row][k] * W[k][h]
// blockDim = 512: 4 row-groups x 128 columns. W staged in LDS (64 KB).
__global__ __launch_bounds__(512) void k_gemm_scale(
    const float* __restrict__ x, const float* __restrict__ W,
    const float* __restrict__ dinv, float* __restrict__ y, int n) {
    __shared__ float Wl[FDIM * HDIM];   // 64 KB
    __shared__ float xs[4][FDIM];       // 2 KB
    const int t = threadIdx.x;
    const int h = t & (HDIM - 1);
    const int g = t >> 7;  // 0..3
    {
        const float4* W4 = (const float4*)W;
        float4* Wl4 = (float4*)Wl;
        for (int i = t; i < FDIM * HDIM / 4; i += 512) Wl4[i] = W4[i];
    }
    __syncthreads();
    const int nq = (n + 3) >> 2;
    for (int q = blockIdx.x; q < nq; q += gridDim.x) {
        const int row = q * 4 + g;
        if (row < n) xs[g][h] = x[(size_t)row * FDIM + h];
        __syncthreads();
        if (row < n) {
            float acc = 0.0f;
#pragma unroll
            for (int k = 0; k < FDIM; ++k)
                acc = fmaf(xs[g][k], Wl[k * HDIM + h], acc);
            y[(size_t)row * HDIM + h] = acc * dinv[row];
        }
        __syncthreads();
    }
}

// For each edge (s,d): acc[d][:] += y[s][:]. 32 lanes x float4 per edge.
__global__ __launch_bounds__(256) void k_scatter(
    const int* __restrict__ src, const int* __restrict__ dst,
    const float* __restrict__ y, float* __restrict__ acc, int e) {
    const int t = threadIdx.x;
    const int lane = t & 31;       // float4 slot within the row
    const int sub = t >> 5;        // 8 edges per block
    const long long eid = (long long)blockIdx.x * 8 + sub;
    if (eid < e) {
        const int s = src[eid];
        const int d = dst[eid];
        const float4 v = ((const float4*)(y + (size_t)s * HDIM))[lane];
        float* a = acc + (size_t)d * HDIM + (size_t)lane * 4;
        atomicAdd(a + 0, v.x);
        atomicAdd(a + 1, v.y);
        atomicAdd(a + 2, v.z);
        atomicAdd(a + 3, v.w);
    }
}

// out = relu(dinv[row] * (y + acc) + b), in place over d_out (holds y).
__global__ __launch_bounds__(256) void k_finalize(
    float* __restrict__ out, const float* __restrict__ acc,
    const float* __restrict__ dinv, const float* __restrict__ bias, int n) {
    const size_t idx = (size_t)blockIdx.x * 256 + threadIdx.x;  // float4 index
    const size_t total = (size_t)n * (HDIM / 4);
    if (idx < total) {
        const int row = (int)(idx >> 5);
        const int q = (int)(idx & 31);
        const float di = dinv[row];
        const float4 yv = ((const float4*)out)[idx];
        const float4 av = ((const float4*)acc)[idx];
        const float4 bv = ((const float4*)bias)[q];
        float4 r;
        r.x = fmaxf(fmaf(di, yv.x + av.x, bv.x), 0.0f);
        r.y = fmaxf(fmaf(di, yv.y + av.y, bv.y), 0.0f);
        r.z = fmaxf(fmaf(di, yv.z + av.z, bv.z), 0.0f);
        r.w = fmaxf(fmaf(di, yv.w + av.w, bv.w), 0.0f);
        ((float4*)out)[idx] = r;
    }
}

extern "C" void kernel_launch(void* const* d_in, const int* in_sizes, int n_in,
                              void* d_out, int out_size, void* d_ws, size_t ws_size,
                              hipStream_t stream) {
    const float* x = (const float*)d_in[0];
    const float* W = (const float*)d_in[1];
    const float* b = (const float*)d_in[2];
    const int* ei = (const int*)d_in[3];
    float* out = (float*)d_out;

    const int H = in_sizes[2];            // 128
    const int F = in_sizes[1] / H;        // 128
    const int N = in_sizes[0] / F;        // 50000
    const int E = in_sizes[3] / 2;        // 600000
    const int* srcp = ei;
    const int* dstp = ei + E;

    float* deg = (float*)d_ws;  // becomes dinv after k_rsqrt
    const size_t accOff = (((size_t)N * sizeof(float)) + 255) & ~(size_t)255;
    float* acc = (float*)((char*)d_ws + accOff);

    hipMemsetAsync(acc, 0, (size_t)N * H * sizeof(float), stream);
    k_init_deg<<<(N + 255) / 256, 256, 0, stream>>>(deg, N);
    k_count_deg<<<(E + 255) / 256, 256, 0, stream>>>(dstp, deg, E);
    k_rsqrt<<<(N + 255) / 256, 256, 0, stream>>>(deg, N);
    k_gemm_scale<<<512, 512, 0, stream>>>(x, W, deg, out, N);
    k_scatter<<<(E + 7) / 8, 256, 0, stream>>>(srcp, dstp, out, acc, E);
    k_finalize<<<(int)(((size_t)N * (H / 4) + 255) / 256), 256, 0, stream>>>(out, acc, deg, b, N);
}

// Round 2
// 205.450 us; speedup vs baseline: 5.5795x; 5.5795x over previous
//
#include <hip/hip_runtime.h>

// GCNConv forward on MI355X — aggregate-then-transform formulation.
//
//   out[t] = relu( ( dinv[t] * sum_{s in N(t) ∪ {t}} dinv[s] * x[s] ) @ W + b )
//
// Pipeline:
//   1. deg histogram over dst (int atomics), dinv = rsqrt(deg+1)
//   2. exclusive scan -> rowptr; bucket-fill -> elist (CSR by dst)
//   3. pull-gather: z[t] = dinv[t] * (dinv[t]*x[t] + sum dinv[s]*x[s])  -> d_out
//   4. in-place GEMM + bias + relu on d_out (W staged in LDS)
//
// d_ws layout: deg | dinv | rowptr | cursor | partials | elist  (~3.2 MB)

#define FDIM 128
#define HDIM 128
#define SCAN_CHUNK 1024  // elements per scan1 block (256 thr x 4)

__global__ __launch_bounds__(256) void k_count(const int* __restrict__ dst,
                                               int* __restrict__ deg, int e) {
    int i = blockIdx.x * 256 + threadIdx.x;
    if (i < e) atomicAdd(&deg[dst[i]], 1);
}

__global__ __launch_bounds__(256) void k_dinv(const int* __restrict__ deg,
                                              float* __restrict__ dinv, int n) {
    int i = blockIdx.x * 256 + threadIdx.x;
    if (i < n) dinv[i] = rsqrtf((float)deg[i] + 1.0f);  // +1 self-loop
}

// scan1: per-block exclusive prefix (without block offset) + block totals
__global__ __launch_bounds__(256) void k_scan1(const int* __restrict__ deg,
                                               int* __restrict__ rowptr,
                                               int* __restrict__ partials, int n) {
    __shared__ int sdata[256];
    const int tid = threadIdx.x;
    const int base = blockIdx.x * SCAN_CHUNK + tid * 4;
    int v[4];
    int s = 0;
#pragma unroll
    for (int j = 0; j < 4; ++j) {
        int idx = base + j;
        v[j] = (idx < n) ? deg[idx] : 0;
        s += v[j];
    }
    sdata[tid] = s;
    __syncthreads();
    for (int off = 1; off < 256; off <<= 1) {
        int t = (tid >= off) ? sdata[tid - off] : 0;
        __syncthreads();
        sdata[tid] += t;
        __syncthreads();
    }
    int run = sdata[tid] - s;  // exclusive offset of this thread within block
#pragma unroll
    for (int j = 0; j < 4; ++j) {
        int idx = base + j;
        if (idx < n) rowptr[idx] = run;
        run += v[j];
    }
    if (tid == 255) partials[blockIdx.x] = sdata[255];
}

// scan2: exclusive scan of block partials (nb <= 64) via wave shuffle
__global__ __launch_bounds__(64) void k_scan2(int* __restrict__ partials, int nb) {
    int l = threadIdx.x;
    int v = (l < nb) ? partials[l] : 0;
    int inc = v;
    for (int off = 1; off < 64; off <<= 1) {
        int t = __shfl_up(inc, off);
        if (l >= off) inc += t;
    }
    if (l < nb) partials[l] = inc - v;
}

// scan3: add block offsets, init cursor, set rowptr[n] = e
__global__ __launch_bounds__(256) void k_scan3(int* __restrict__ rowptr,
                                               const int* __restrict__ partials,
                                               int* __restrict__ cursor, int n, int e) {
    int i = blockIdx.x * 256 + threadIdx.x;
    if (i < n) {
        int r = rowptr[i] + partials[i >> 10];  // SCAN_CHUNK = 1024
        rowptr[i] = r;
        cursor[i] = r;
    }
    if (i == n) rowptr[n] = e;
}

__global__ __launch_bounds__(256) void k_fill(const int* __restrict__ src,
                                              const int* __restrict__ dst,
                                              int* __restrict__ cursor,
                                              int* __restrict__ elist, int e) {
    int i = blockIdx.x * 256 + threadIdx.x;
    if (i < e) {
        int slot = atomicAdd(&cursor[dst[i]], 1);
        elist[slot] = src[i];
    }
}

// Pull-gather: 32 lanes per node (float4 over 128 cols), 8 nodes per block.
// z[t] = dinv[t] * ( dinv[t]*x[t] + sum_{s in in(t)} dinv[s]*x[s] )
__global__ __launch_bounds__(256) void k_gather(const float* __restrict__ x,
                                                const float* __restrict__ dinv,
                                                const int* __restrict__ rowptr,
                                                const int* __restrict__ elist,
                                                float* __restrict__ z, int n) {
    const int lane = threadIdx.x & 31;
    const int node = blockIdx.x * 8 + (threadIdx.x >> 5);
    if (node >= n) return;
    const float di = dinv[node];
    float4 v = ((const float4*)(x + (size_t)node * FDIM))[lane];
    float4 sum;
    sum.x = di * v.x; sum.y = di * v.y; sum.z = di * v.z; sum.w = di * v.w;
    const int beg = rowptr[node], end = rowptr[node + 1];
    for (int j = beg; j < end; ++j) {
        const int s = elist[j];
        const float ds = dinv[s];
        const float4 u = ((const float4*)(x + (size_t)s * FDIM))[lane];
        sum.x = fmaf(ds, u.x, sum.x);
        sum.y = fmaf(ds, u.y, sum.y);
        sum.z = fmaf(ds, u.z, sum.z);
        sum.w = fmaf(ds, u.w, sum.w);
    }
    float4 o;
    o.x = di * sum.x; o.y = di * sum.y; o.z = di * sum.z; o.w = di * sum.w;
    ((float4*)(z + (size_t)node * FDIM))[lane] = o;
}

// In-place GEMM + bias + relu: out_row = relu(z_row @ W + b). Each row is
// read fully into LDS before being overwritten -> in-place safe per block.
__global__ __launch_bounds__(512) void k_gemm_relu(const float* __restrict__ W,
                                                   const float* __restrict__ bias,
                                                   float* __restrict__ zo, int n) {
    __shared__ float Wl[FDIM * HDIM];  // 64 KB
    __shared__ float xs[4][FDIM];      // 2 KB
    const int t = threadIdx.x;
    const int h = t & (HDIM - 1);
    const int g = t >> 7;  // 0..3
    {
        const float4* W4 = (const float4*)W;
        float4* Wl4 = (float4*)Wl;
        for (int i = t; i < FDIM * HDIM / 4; i += 512) Wl4[i] = W4[i];
    }
    __syncthreads();
    const float bv = bias[h];
    const int nq = (n + 3) >> 2;
    for (int q = blockIdx.x; q < nq; q += gridDim.x) {
        const int row = q * 4 + g;
        if (row < n) xs[g][h] = zo[(size_t)row * HDIM + h];
        __syncthreads();
        if (row < n) {
            float acc = bv;
#pragma unroll
            for (int k = 0; k < FDIM; ++k)
                acc = fmaf(xs[g][k], Wl[k * HDIM + h], acc);
            zo[(size_t)row * HDIM + h] = fmaxf(acc, 0.0f);
        }
        __syncthreads();
    }
}

extern "C" void kernel_launch(void* const* d_in, const int* in_sizes, int n_in,
                              void* d_out, int out_size, void* d_ws, size_t ws_size,
                              hipStream_t stream) {
    const float* x = (const float*)d_in[0];
    const float* W = (const float*)d_in[1];
    const float* b = (const float*)d_in[2];
    const int* ei = (const int*)d_in[3];
    float* out = (float*)d_out;

    const int H = in_sizes[2];      // 128
    const int F = in_sizes[1] / H;  // 128
    const int N = in_sizes[0] / F;  // 50000
    const int E = in_sizes[3] / 2;  // 600000
    const int* srcp = ei;
    const int* dstp = ei + E;

    auto align256 = [](size_t v) { return (v + 255) & ~(size_t)255; };
    char* ws = (char*)d_ws;
    size_t off = 0;
    int* deg = (int*)(ws + off);      off += align256((size_t)N * 4);
    float* dinv = (float*)(ws + off); off += align256((size_t)N * 4);
    int* rowptr = (int*)(ws + off);   off += align256((size_t)(N + 1) * 4);
    int* cursor = (int*)(ws + off);   off += align256((size_t)N * 4);
    int* partials = (int*)(ws + off); off += 256;
    int* elist = (int*)(ws + off);    off += align256((size_t)E * 4);

    const int nblk_scan1 = (N + SCAN_CHUNK - 1) / SCAN_CHUNK;  // 49 (<=64)

    hipMemsetAsync(deg, 0, (size_t)N * 4, stream);
    k_count<<<(E + 255) / 256, 256, 0, stream>>>(dstp, deg, E);
    k_dinv<<<(N + 255) / 256, 256, 0, stream>>>(deg, dinv, N);
    k_scan1<<<nblk_scan1, 256, 0, stream>>>(deg, rowptr, partials, N);
    k_scan2<<<1, 64, 0, stream>>>(partials, nblk_scan1);
    k_scan3<<<(N + 1 + 255) / 256, 256, 0, stream>>>(rowptr, partials, cursor, N, E);
    k_fill<<<(E + 255) / 256, 256, 0, stream>>>(srcp, dstp, cursor, elist, E);
    k_gather<<<(N + 7) / 8, 256, 0, stream>>>(x, dinv, rowptr, elist, out, N);
    k_gemm_relu<<<512, 512, 0, stream>>>(W, b, out, N);
}

// Round 3
// 142.610 us; speedup vs baseline: 8.0380x; 1.4406x over previous
//
#include <hip/hip_runtime.h>
#include <stdint.h>

// GCNConv forward on MI355X — aggregate-then-transform, bf16 MFMA GEMM.
//
//   out[t] = relu( ( dinv[t] * sum_{s in N(t) ∪ {t}} dinv[s] * x[s] ) @ W + b )
//
// Fast path:
//   1. deg histogram (int atomics) -> dinv = rsqrt(deg+1)
//   2. xs[s] = bf16(dinv[s] * x[s])           (pre-scaled features, 12.8 MB)
//   3. CSR by dst (scan + bucket fill)
//   4. pull-gather: z[t] = bf16(dinv[t] * (xs[t] + sum xs[s]))  row-sum only
//   5. bf16 MFMA GEMM (16x16x32) + bias + relu -> d_out (fp32)
// Fallback (ws too small): R2 fp32 gather + fp32 LDS GEMM.

#define FDIM 128
#define HDIM 128
#define SCAN_CHUNK 1024

using s8v  = __attribute__((ext_vector_type(8))) short;   // 8 bf16 = 4 VGPR
using f32x4 = __attribute__((ext_vector_type(4))) float;  // MFMA C/D

__device__ __forceinline__ unsigned bf16rn(float f) {
    unsigned u = __float_as_uint(f);
    return (u + 0x7fffu + ((u >> 16) & 1u)) >> 16;  // round-to-nearest-even
}
__device__ __forceinline__ void upadd(unsigned w, float& lo, float& hi) {
    lo += __uint_as_float(w << 16);
    hi += __uint_as_float(w & 0xffff0000u);
}

// ---------------- degree / dinv ----------------
__global__ __launch_bounds__(256) void k_count(const int* __restrict__ dst,
                                               int* __restrict__ deg, int e) {
    int i = blockIdx.x * 256 + threadIdx.x;
    if (i < e) atomicAdd(&deg[dst[i]], 1);
}

__global__ __launch_bounds__(256) void k_dinv(const int* __restrict__ deg,
                                              float* __restrict__ dinv, int n) {
    int i = blockIdx.x * 256 + threadIdx.x;
    if (i < n) dinv[i] = rsqrtf((float)deg[i] + 1.0f);
}

// ---------------- scan -> rowptr ----------------
__global__ __launch_bounds__(256) void k_scan1(const int* __restrict__ deg,
                                               int* __restrict__ rowptr,
                                               int* __restrict__ partials, int n) {
    __shared__ int sdata[256];
    const int tid = threadIdx.x;
    const int base = blockIdx.x * SCAN_CHUNK + tid * 4;
    int v[4];
    int s = 0;
#pragma unroll
    for (int j = 0; j < 4; ++j) {
        int idx = base + j;
        v[j] = (idx < n) ? deg[idx] : 0;
        s += v[j];
    }
    sdata[tid] = s;
    __syncthreads();
    for (int off = 1; off < 256; off <<= 1) {
        int t = (tid >= off) ? sdata[tid - off] : 0;
        __syncthreads();
        sdata[tid] += t;
        __syncthreads();
    }
    int run = sdata[tid] - s;
#pragma unroll
    for (int j = 0; j < 4; ++j) {
        int idx = base + j;
        if (idx < n) rowptr[idx] = run;
        run += v[j];
    }
    if (tid == 255) partials[blockIdx.x] = sdata[255];
}

__global__ __launch_bounds__(64) void k_scan2(int* __restrict__ partials, int nb) {
    int l = threadIdx.x;
    int v = (l < nb) ? partials[l] : 0;
    int inc = v;
    for (int off = 1; off < 64; off <<= 1) {
        int t = __shfl_up(inc, off);
        if (l >= off) inc += t;
    }
    if (l < nb) partials[l] = inc - v;
}

__global__ __launch_bounds__(256) void k_scan3(int* __restrict__ rowptr,
                                               const int* __restrict__ partials,
                                               int* __restrict__ cursor, int n, int e) {
    int i = blockIdx.x * 256 + threadIdx.x;
    if (i < n) {
        int r = rowptr[i] + partials[i >> 10];
        rowptr[i] = r;
        cursor[i] = r;
    }
    if (i == n) rowptr[n] = e;
}

__global__ __launch_bounds__(256) void k_fill(const int* __restrict__ src,
                                              const int* __restrict__ dst,
                                              int* __restrict__ cursor,
                                              int* __restrict__ elist, int e) {
    int i = blockIdx.x * 256 + threadIdx.x;
    if (i < e) {
        int slot = atomicAdd(&cursor[dst[i]], 1);
        elist[slot] = src[i];
    }
}

// ---------------- fast path: bf16 ----------------
// xs chunk (8 elems) per thread: xs = bf16(dinv[row] * x)
__global__ __launch_bounds__(256) void k_prescale(const float* __restrict__ x,
                                                  const float* __restrict__ dinv,
                                                  uint4* __restrict__ xsb, int n) {
    const long long idx = (long long)blockIdx.x * 256 + threadIdx.x;  // 16B chunk
    if (idx >= (long long)n * (FDIM / 8)) return;
    const int node = (int)(idx >> 4);
    const float di = dinv[node];
    const float4* xp = (const float4*)x + idx * 2;
    const float4 a = xp[0], b = xp[1];
    uint4 o;
    o.x = bf16rn(a.x * di) | (bf16rn(a.y * di) << 16);
    o.y = bf16rn(a.z * di) | (bf16rn(a.w * di) << 16);
    o.z = bf16rn(b.x * di) | (bf16rn(b.y * di) << 16);
    o.w = bf16rn(b.z * di) | (bf16rn(b.w * di) << 16);
    xsb[idx] = o;
}

// W fp32 [128][128] -> chunk-major bf16: Warr[(chunk*128 + n)] (16B unit)
// holds W[chunk*8 .. chunk*8+7][n]  (i.e. W^T rows, 8 k-values per unit)
__global__ __launch_bounds__(256) void k_warr(const float* __restrict__ W,
                                              uint4* __restrict__ Warr) {
    const int t = blockIdx.x * 256 + threadIdx.x;
    if (t >= (FDIM / 8) * HDIM) return;
    const int chunk = t >> 7, nn = t & 127;
    float v[8];
#pragma unroll
    for (int j = 0; j < 8; ++j) v[j] = W[(chunk * 8 + j) * HDIM + nn];
    uint4 o;
    o.x = bf16rn(v[0]) | (bf16rn(v[1]) << 16);
    o.y = bf16rn(v[2]) | (bf16rn(v[3]) << 16);
    o.z = bf16rn(v[4]) | (bf16rn(v[5]) << 16);
    o.w = bf16rn(v[6]) | (bf16rn(v[7]) << 16);
    Warr[t] = o;
}

// Pull-gather over bf16 rows: 16 lanes x 16B per node, fp32 accumulate.
// z[t] = bf16( dinv[t] * (xs[t] + sum_{s in in(t)} xs[s]) )
__global__ __launch_bounds__(256) void k_gather_bf16(const uint4* __restrict__ xsb,
                                                     const float* __restrict__ dinv,
                                                     const int* __restrict__ rowptr,
                                                     const int* __restrict__ elist,
                                                     uint4* __restrict__ zb, int n) {
    const int q = threadIdx.x & 15;
    const int node = blockIdx.x * 16 + (threadIdx.x >> 4);
    if (node >= n) return;
    float a0, a1, a2, a3, a4, a5, a6, a7;
    {
        const uint4 v = xsb[node * 16 + q];
        a0 = __uint_as_float(v.x << 16); a1 = __uint_as_float(v.x & 0xffff0000u);
        a2 = __uint_as_float(v.y << 16); a3 = __uint_as_float(v.y & 0xffff0000u);
        a4 = __uint_as_float(v.z << 16); a5 = __uint_as_float(v.z & 0xffff0000u);
        a6 = __uint_as_float(v.w << 16); a7 = __uint_as_float(v.w & 0xffff0000u);
    }
    const int beg = rowptr[node], end = rowptr[node + 1];
    for (int j = beg; j < end; ++j) {
        const int s = elist[j];
        const uint4 u = xsb[s * 16 + q];
        upadd(u.x, a0, a1);
        upadd(u.y, a2, a3);
        upadd(u.z, a4, a5);
        upadd(u.w, a6, a7);
    }
    const float di = dinv[node];
    uint4 o;
    o.x = bf16rn(a0 * di) | (bf16rn(a1 * di) << 16);
    o.y = bf16rn(a2 * di) | (bf16rn(a3 * di) << 16);
    o.z = bf16rn(a4 * di) | (bf16rn(a5 * di) << 16);
    o.w = bf16rn(a6 * di) | (bf16rn(a7 * di) << 16);
    zb[node * 16 + q] = o;
}

// bf16 MFMA GEMM: out = relu(z @ W + b). Block = 128 thr (2 waves),
// 64 rows/wave (4 row-tiles of 16). W staged in LDS chunk-major (32 KB),
// B-fragment ds_read_b128 conflict-free (lanes 0-15 consecutive 16B).
__global__ __launch_bounds__(128) void k_gemm_mfma(const uint4* __restrict__ Warr,
                                                   const float* __restrict__ bias,
                                                   const unsigned short* __restrict__ zb,
                                                   float* __restrict__ out, int n) {
    __shared__ uint4 Wl[(FDIM / 8) * HDIM];  // 32 KB
    const int t = threadIdx.x;
    for (int i = t; i < (FDIM / 8) * HDIM; i += 128) Wl[i] = Warr[i];
    __syncthreads();
    const int l = t & 63, wave = t >> 6;
    const int l16 = l & 15, lg = l >> 4;
    const int base = blockIdx.x * 128 + wave * 64;

    s8v a[4][4];
#pragma unroll
    for (int rt = 0; rt < 4; ++rt) {
        int row = base + rt * 16 + l16;
        if (row > n - 1) row = n - 1;
        const s8v* zr = (const s8v*)(zb + (size_t)row * HDIM);
#pragma unroll
        for (int ks = 0; ks < 4; ++ks) a[rt][ks] = zr[ks * 4 + lg];
    }

#pragma unroll
    for (int nt = 0; nt < 8; ++nt) {
        const float bv = bias[nt * 16 + l16];
        f32x4 acc[4];
#pragma unroll
        for (int rt = 0; rt < 4; ++rt) acc[rt] = (f32x4){0.f, 0.f, 0.f, 0.f};
#pragma unroll
        for (int ks = 0; ks < 4; ++ks) {
            const s8v bfr = *(const s8v*)&Wl[(ks * 4 + lg) * 128 + nt * 16 + l16];
            acc[0] = __builtin_amdgcn_mfma_f32_16x16x32_bf16(a[0][ks], bfr, acc[0], 0, 0, 0);
            acc[1] = __builtin_amdgcn_mfma_f32_16x16x32_bf16(a[1][ks], bfr, acc[1], 0, 0, 0);
            acc[2] = __builtin_amdgcn_mfma_f32_16x16x32_bf16(a[2][ks], bfr, acc[2], 0, 0, 0);
            acc[3] = __builtin_amdgcn_mfma_f32_16x16x32_bf16(a[3][ks], bfr, acc[3], 0, 0, 0);
        }
        const int col = nt * 16 + l16;
#pragma unroll
        for (int rt = 0; rt < 4; ++rt) {
#pragma unroll
            for (int r = 0; r < 4; ++r) {
                const int row = base + rt * 16 + lg * 4 + r;
                if (row < n) out[(size_t)row * HDIM + col] = fmaxf(acc[rt][r] + bv, 0.0f);
            }
        }
    }
}

// ---------------- fallback path: fp32 (R2, proven) ----------------
__global__ __launch_bounds__(256) void k_gather_f32(const float* __restrict__ x,
                                                    const float* __restrict__ dinv,
                                                    const int* __restrict__ rowptr,
                                                    const int* __restrict__ elist,
                                                    float* __restrict__ z, int n) {
    const int lane = threadIdx.x & 31;
    const int node = blockIdx.x * 8 + (threadIdx.x >> 5);
    if (node >= n) return;
    const float di = dinv[node];
    float4 v = ((const float4*)(x + (size_t)node * FDIM))[lane];
    float4 sum;
    sum.x = di * v.x; sum.y = di * v.y; sum.z = di * v.z; sum.w = di * v.w;
    const int beg = rowptr[node], end = rowptr[node + 1];
    for (int j = beg; j < end; ++j) {
        const int s = elist[j];
        const float ds = dinv[s];
        const float4 u = ((const float4*)(x + (size_t)s * FDIM))[lane];
        sum.x = fmaf(ds, u.x, sum.x);
        sum.y = fmaf(ds, u.y, sum.y);
        sum.z = fmaf(ds, u.z, sum.z);
        sum.w = fmaf(ds, u.w, sum.w);
    }
    float4 o;
    o.x = di * sum.x; o.y = di * sum.y; o.z = di * sum.z; o.w = di * sum.w;
    ((float4*)(z + (size_t)node * FDIM))[lane] = o;
}

__global__ __launch_bounds__(512) void k_gemm_relu(const float* __restrict__ W,
                                                   const float* __restrict__ bias,
                                                   float* __restrict__ zo, int n) {
    __shared__ float Wl[FDIM * HDIM];
    __shared__ float xs[4][FDIM];
    const int t = threadIdx.x;
    const int h = t & (HDIM - 1);
    const int g = t >> 7;
    {
        const float4* W4 = (const float4*)W;
        float4* Wl4 = (float4*)Wl;
        for (int i = t; i < FDIM * HDIM / 4; i += 512) Wl4[i] = W4[i];
    }
    __syncthreads();
    const float bv = bias[h];
    const int nq = (n + 3) >> 2;
    for (int q = blockIdx.x; q < nq; q += gridDim.x) {
        const int row = q * 4 + g;
        if (row < n) xs[g][h] = zo[(size_t)row * HDIM + h];
        __syncthreads();
        if (row < n) {
            float acc = bv;
#pragma unroll
            for (int k = 0; k < FDIM; ++k)
                acc = fmaf(xs[g][k], Wl[k * HDIM + h], acc);
            zo[(size_t)row * HDIM + h] = fmaxf(acc, 0.0f);
        }
        __syncthreads();
    }
}

extern "C" void kernel_launch(void* const* d_in, const int* in_sizes, int n_in,
                              void* d_out, int out_size, void* d_ws, size_t ws_size,
                              hipStream_t stream) {
    const float* x = (const float*)d_in[0];
    const float* W = (const float*)d_in[1];
    const float* b = (const float*)d_in[2];
    const int* ei = (const int*)d_in[3];
    float* out = (float*)d_out;

    const int H = in_sizes[2];      // 128
    const int F = in_sizes[1] / H;  // 128
    const int N = in_sizes[0] / F;  // 50000
    const int E = in_sizes[3] / 2;  // 600000
    const int* srcp = ei;
    const int* dstp = ei + E;

    auto align256 = [](size_t v) { return (v + 255) & ~(size_t)255; };
    char* ws = (char*)d_ws;
    size_t off = 0;
    int* deg = (int*)(ws + off);      off += align256((size_t)N * 4);
    float* dinv = (float*)(ws + off); off += align256((size_t)N * 4);
    int* rowptr = (int*)(ws + off);   off += align256((size_t)(N + 1) * 4);
    int* cursor = (int*)(ws + off);   off += align256((size_t)N * 4);
    int* partials = (int*)(ws + off); off += 256;
    int* elist = (int*)(ws + off);    off += align256((size_t)E * 4);
    uint4* xsb = (uint4*)(ws + off);  off += align256((size_t)N * FDIM * 2);
    uint4* zb = (uint4*)(ws + off);   off += align256((size_t)N * FDIM * 2);
    uint4* Warr = (uint4*)(ws + off); off += align256((size_t)(FDIM / 8) * HDIM * 16);
    const bool fast = (ws_size >= off);

    const int nblk_scan1 = (N + SCAN_CHUNK - 1) / SCAN_CHUNK;

    hipMemsetAsync(deg, 0, (size_t)N * 4, stream);
    k_count<<<(E + 255) / 256, 256, 0, stream>>>(dstp, deg, E);
    k_dinv<<<(N + 255) / 256, 256, 0, stream>>>(deg, dinv, N);
    k_scan1<<<nblk_scan1, 256, 0, stream>>>(deg, rowptr, partials, N);
    k_scan2<<<1, 64, 0, stream>>>(partials, nblk_scan1);
    k_scan3<<<(N + 1 + 255) / 256, 256, 0, stream>>>(rowptr, partials, cursor, N, E);
    k_fill<<<(E + 255) / 256, 256, 0, stream>>>(srcp, dstp, cursor, elist, E);

    if (fast) {
        k_warr<<<((FDIM / 8) * HDIM + 255) / 256, 256, 0, stream>>>(W, Warr);
        const long long nchunks = (long long)N * (FDIM / 8);
        k_prescale<<<(int)((nchunks + 255) / 256), 256, 0, stream>>>(x, dinv, xsb, N);
        k_gather_bf16<<<(N + 15) / 16, 256, 0, stream>>>(xsb, dinv, rowptr, elist, zb, N);
        k_gemm_mfma<<<(N + 127) / 128, 128, 0, stream>>>(Warr, b,
                                                         (const unsigned short*)zb, out, N);
    } else {
        k_gather_f32<<<(N + 7) / 8, 256, 0, stream>>>(x, dinv, rowptr, elist, out, N);
        k_gemm_relu<<<512, 512, 0, stream>>>(W, b, out, N);
    }
}

// Round 4
// 141.342 us; speedup vs baseline: 8.1101x; 1.0090x over previous
//
#include <hip/hip_runtime.h>
#include <stdint.h>

// GCNConv forward on MI355X — aggregate-then-transform, bf16 MFMA GEMM.
//
//   out[t] = relu( ( dinv[t] * sum_{s in N(t) ∪ {t}} dinv[s] * x[s] ) @ W + b )
//
// Fast path:
//   1. deg histogram (int atomics) -> dinv = rsqrt(deg+1)  (dinv fused in scan1)
//   2. xs[s] = bf16(dinv[s] * x[s])           (pre-scaled features, 12.8 MB)
//   3. CSR by dst (scan + bucket fill)
//   4. pull-gather: z[t] = bf16(dinv[t] * (xs[t] + sum xs[s]))  row-sum only
//   5. bf16 MFMA GEMM (16x16x32) + bias + relu -> d_out (fp32)
// Fallback (ws too small): fp32 gather + fp32 LDS GEMM.
//
// R4 changes: hipMemsetAsync(deg) -> k_zero (rocclr fillBuffer was 42 us for
// 200 KB, 30% of total); k_dinv folded into k_scan1.

#define FDIM 128
#define HDIM 128
#define SCAN_CHUNK 1024

using s8v  = __attribute__((ext_vector_type(8))) short;   // 8 bf16 = 4 VGPR
using f32x4 = __attribute__((ext_vector_type(4))) float;  // MFMA C/D

__device__ __forceinline__ unsigned bf16rn(float f) {
    unsigned u = __float_as_uint(f);
    return (u + 0x7fffu + ((u >> 16) & 1u)) >> 16;  // round-to-nearest-even
}
__device__ __forceinline__ void upadd(unsigned w, float& lo, float& hi) {
    lo += __uint_as_float(w << 16);
    hi += __uint_as_float(w & 0xffff0000u);
}

__global__ __launch_bounds__(256) void k_zero(int* __restrict__ p, int n) {
    int i = blockIdx.x * 256 + threadIdx.x;
    if (i < n) p[i] = 0;
}

// ---------------- degree ----------------
__global__ __launch_bounds__(256) void k_count(const int* __restrict__ dst,
                                               int* __restrict__ deg, int e) {
    int i = blockIdx.x * 256 + threadIdx.x;
    if (i < e) atomicAdd(&deg[dst[i]], 1);
}

// ---------------- scan -> rowptr (+ dinv, fused) ----------------
__global__ __launch_bounds__(256) void k_scan1(const int* __restrict__ deg,
                                               int* __restrict__ rowptr,
                                               int* __restrict__ partials,
                                               float* __restrict__ dinv, int n) {
    __shared__ int sdata[256];
    const int tid = threadIdx.x;
    const int base = blockIdx.x * SCAN_CHUNK + tid * 4;
    int v[4];
    int s = 0;
#pragma unroll
    for (int j = 0; j < 4; ++j) {
        int idx = base + j;
        v[j] = (idx < n) ? deg[idx] : 0;
        if (idx < n) dinv[idx] = rsqrtf((float)v[j] + 1.0f);  // +1 self-loop
        s += v[j];
    }
    sdata[tid] = s;
    __syncthreads();
    for (int off = 1; off < 256; off <<= 1) {
        int t = (tid >= off) ? sdata[tid - off] : 0;
        __syncthreads();
        sdata[tid] += t;
        __syncthreads();
    }
    int run = sdata[tid] - s;
#pragma unroll
    for (int j = 0; j < 4; ++j) {
        int idx = base + j;
        if (idx < n) rowptr[idx] = run;
        run += v[j];
    }
    if (tid == 255) partials[blockIdx.x] = sdata[255];
}

__global__ __launch_bounds__(64) void k_scan2(int* __restrict__ partials, int nb) {
    int l = threadIdx.x;
    int v = (l < nb) ? partials[l] : 0;
    int inc = v;
    for (int off = 1; off < 64; off <<= 1) {
        int t = __shfl_up(inc, off);
        if (l >= off) inc += t;
    }
    if (l < nb) partials[l] = inc - v;
}

__global__ __launch_bounds__(256) void k_scan3(int* __restrict__ rowptr,
                                               const int* __restrict__ partials,
                                               int* __restrict__ cursor, int n, int e) {
    int i = blockIdx.x * 256 + threadIdx.x;
    if (i < n) {
        int r = rowptr[i] + partials[i >> 10];
        rowptr[i] = r;
        cursor[i] = r;
    }
    if (i == n) rowptr[n] = e;
}

__global__ __launch_bounds__(256) void k_fill(const int* __restrict__ src,
                                              const int* __restrict__ dst,
                                              int* __restrict__ cursor,
                                              int* __restrict__ elist, int e) {
    int i = blockIdx.x * 256 + threadIdx.x;
    if (i < e) {
        int slot = atomicAdd(&cursor[dst[i]], 1);
        elist[slot] = src[i];
    }
}

// ---------------- fast path: bf16 ----------------
__global__ __launch_bounds__(256) void k_prescale(const float* __restrict__ x,
                                                  const float* __restrict__ dinv,
                                                  uint4* __restrict__ xsb, int n) {
    const long long idx = (long long)blockIdx.x * 256 + threadIdx.x;  // 16B chunk
    if (idx >= (long long)n * (FDIM / 8)) return;
    const int node = (int)(idx >> 4);
    const float di = dinv[node];
    const float4* xp = (const float4*)x + idx * 2;
    const float4 a = xp[0], b = xp[1];
    uint4 o;
    o.x = bf16rn(a.x * di) | (bf16rn(a.y * di) << 16);
    o.y = bf16rn(a.z * di) | (bf16rn(a.w * di) << 16);
    o.z = bf16rn(b.x * di) | (bf16rn(b.y * di) << 16);
    o.w = bf16rn(b.z * di) | (bf16rn(b.w * di) << 16);
    xsb[idx] = o;
}

// W fp32 [128][128] -> chunk-major bf16: Warr[chunk*128 + n] (16B unit)
// holds W[chunk*8 .. chunk*8+7][n]
__global__ __launch_bounds__(256) void k_warr(const float* __restrict__ W,
                                              uint4* __restrict__ Warr) {
    const int t = blockIdx.x * 256 + threadIdx.x;
    if (t >= (FDIM / 8) * HDIM) return;
    const int chunk = t >> 7, nn = t & 127;
    float v[8];
#pragma unroll
    for (int j = 0; j < 8; ++j) v[j] = W[(chunk * 8 + j) * HDIM + nn];
    uint4 o;
    o.x = bf16rn(v[0]) | (bf16rn(v[1]) << 16);
    o.y = bf16rn(v[2]) | (bf16rn(v[3]) << 16);
    o.z = bf16rn(v[4]) | (bf16rn(v[5]) << 16);
    o.w = bf16rn(v[6]) | (bf16rn(v[7]) << 16);
    Warr[t] = o;
}

// Pull-gather over bf16 rows: 16 lanes x 16B per node, fp32 accumulate.
__global__ __launch_bounds__(256) void k_gather_bf16(const uint4* __restrict__ xsb,
                                                     const float* __restrict__ dinv,
                                                     const int* __restrict__ rowptr,
                                                     const int* __restrict__ elist,
                                                     uint4* __restrict__ zb, int n) {
    const int q = threadIdx.x & 15;
    const int node = blockIdx.x * 16 + (threadIdx.x >> 4);
    if (node >= n) return;
    float a0, a1, a2, a3, a4, a5, a6, a7;
    {
        const uint4 v = xsb[node * 16 + q];
        a0 = __uint_as_float(v.x << 16); a1 = __uint_as_float(v.x & 0xffff0000u);
        a2 = __uint_as_float(v.y << 16); a3 = __uint_as_float(v.y & 0xffff0000u);
        a4 = __uint_as_float(v.z << 16); a5 = __uint_as_float(v.z & 0xffff0000u);
        a6 = __uint_as_float(v.w << 16); a7 = __uint_as_float(v.w & 0xffff0000u);
    }
    const int beg = rowptr[node], end = rowptr[node + 1];
    for (int j = beg; j < end; ++j) {
        const int s = elist[j];
        const uint4 u = xsb[s * 16 + q];
        upadd(u.x, a0, a1);
        upadd(u.y, a2, a3);
        upadd(u.z, a4, a5);
        upadd(u.w, a6, a7);
    }
    const float di = dinv[node];
    uint4 o;
    o.x = bf16rn(a0 * di) | (bf16rn(a1 * di) << 16);
    o.y = bf16rn(a2 * di) | (bf16rn(a3 * di) << 16);
    o.z = bf16rn(a4 * di) | (bf16rn(a5 * di) << 16);
    o.w = bf16rn(a6 * di) | (bf16rn(a7 * di) << 16);
    zb[node * 16 + q] = o;
}

// bf16 MFMA GEMM: out = relu(z @ W + b). 128 thr (2 waves), 64 rows/wave.
__global__ __launch_bounds__(128) void k_gemm_mfma(const uint4* __restrict__ Warr,
                                                   const float* __restrict__ bias,
                                                   const unsigned short* __restrict__ zb,
                                                   float* __restrict__ out, int n) {
    __shared__ uint4 Wl[(FDIM / 8) * HDIM];  // 32 KB
    const int t = threadIdx.x;
    for (int i = t; i < (FDIM / 8) * HDIM; i += 128) Wl[i] = Warr[i];
    __syncthreads();
    const int l = t & 63, wave = t >> 6;
    const int l16 = l & 15, lg = l >> 4;
    const int base = blockIdx.x * 128 + wave * 64;

    s8v a[4][4];
#pragma unroll
    for (int rt = 0; rt < 4; ++rt) {
        int row = base + rt * 16 + l16;
        if (row > n - 1) row = n - 1;
        const s8v* zr = (const s8v*)(zb + (size_t)row * HDIM);
#pragma unroll
        for (int ks = 0; ks < 4; ++ks) a[rt][ks] = zr[ks * 4 + lg];
    }

#pragma unroll
    for (int nt = 0; nt < 8; ++nt) {
        const float bv = bias[nt * 16 + l16];
        f32x4 acc[4];
#pragma unroll
        for (int rt = 0; rt < 4; ++rt) acc[rt] = (f32x4){0.f, 0.f, 0.f, 0.f};
#pragma unroll
        for (int ks = 0; ks < 4; ++ks) {
            const s8v bfr = *(const s8v*)&Wl[(ks * 4 + lg) * 128 + nt * 16 + l16];
            acc[0] = __builtin_amdgcn_mfma_f32_16x16x32_bf16(a[0][ks], bfr, acc[0], 0, 0, 0);
            acc[1] = __builtin_amdgcn_mfma_f32_16x16x32_bf16(a[1][ks], bfr, acc[1], 0, 0, 0);
            acc[2] = __builtin_amdgcn_mfma_f32_16x16x32_bf16(a[2][ks], bfr, acc[2], 0, 0, 0);
            acc[3] = __builtin_amdgcn_mfma_f32_16x16x32_bf16(a[3][ks], bfr, acc[3], 0, 0, 0);
        }
        const int col = nt * 16 + l16;
#pragma unroll
        for (int rt = 0; rt < 4; ++rt) {
#pragma unroll
            for (int r = 0; r < 4; ++r) {
                const int row = base + rt * 16 + lg * 4 + r;
                if (row < n) out[(size_t)row * HDIM + col] = fmaxf(acc[rt][r] + bv, 0.0f);
            }
        }
    }
}

// ---------------- fallback path: fp32 ----------------
__global__ __launch_bounds__(256) void k_gather_f32(const float* __restrict__ x,
                                                    const float* __restrict__ dinv,
                                                    const int* __restrict__ rowptr,
                                                    const int* __restrict__ elist,
                                                    float* __restrict__ z, int n) {
    const int lane = threadIdx.x & 31;
    const int node = blockIdx.x * 8 + (threadIdx.x >> 5);
    if (node >= n) return;
    const float di = dinv[node];
    float4 v = ((const float4*)(x + (size_t)node * FDIM))[lane];
    float4 sum;
    sum.x = di * v.x; sum.y = di * v.y; sum.z = di * v.z; sum.w = di * v.w;
    const int beg = rowptr[node], end = rowptr[node + 1];
    for (int j = beg; j < end; ++j) {
        const int s = elist[j];
        const float ds = dinv[s];
        const float4 u = ((const float4*)(x + (size_t)s * FDIM))[lane];
        sum.x = fmaf(ds, u.x, sum.x);
        sum.y = fmaf(ds, u.y, sum.y);
        sum.z = fmaf(ds, u.z, sum.z);
        sum.w = fmaf(ds, u.w, sum.w);
    }
    float4 o;
    o.x = di * sum.x; o.y = di * sum.y; o.z = di * sum.z; o.w = di * sum.w;
    ((float4*)(z + (size_t)node * FDIM))[lane] = o;
}

__global__ __launch_bounds__(512) void k_gemm_relu(const float* __restrict__ W,
                                                   const float* __restrict__ bias,
                                                   float* __restrict__ zo, int n) {
    __shared__ float Wl[FDIM * HDIM];
    __shared__ float xs[4][FDIM];
    const int t = threadIdx.x;
    const int h = t & (HDIM - 1);
    const int g = t >> 7;
    {
        const float4* W4 = (const float4*)W;
        float4* Wl4 = (float4*)Wl;
        for (int i = t; i < FDIM * HDIM / 4; i += 512) Wl4[i] = W4[i];
    }
    __syncthreads();
    const float bv = bias[h];
    const int nq = (n + 3) >> 2;
    for (int q = blockIdx.x; q < nq; q += gridDim.x) {
        const int row = q * 4 + g;
        if (row < n) xs[g][h] = zo[(size_t)row * HDIM + h];
        __syncthreads();
        if (row < n) {
            float acc = bv;
#pragma unroll
            for (int k = 0; k < FDIM; ++k)
                acc = fmaf(xs[g][k], Wl[k * HDIM + h], acc);
            zo[(size_t)row * HDIM + h] = fmaxf(acc, 0.0f);
        }
        __syncthreads();
    }
}

extern "C" void kernel_launch(void* const* d_in, const int* in_sizes, int n_in,
                              void* d_out, int out_size, void* d_ws, size_t ws_size,
                              hipStream_t stream) {
    const float* x = (const float*)d_in[0];
    const float* W = (const float*)d_in[1];
    const float* b = (const float*)d_in[2];
    const int* ei = (const int*)d_in[3];
    float* out = (float*)d_out;

    const int H = in_sizes[2];      // 128
    const int F = in_sizes[1] / H;  // 128
    const int N = in_sizes[0] / F;  // 50000
    const int E = in_sizes[3] / 2;  // 600000
    const int* srcp = ei;
    const int* dstp = ei + E;

    auto align256 = [](size_t v) { return (v + 255) & ~(size_t)255; };
    char* ws = (char*)d_ws;
    size_t off = 0;
    int* deg = (int*)(ws + off);      off += align256((size_t)N * 4);
    float* dinv = (float*)(ws + off); off += align256((size_t)N * 4);
    int* rowptr = (int*)(ws + off);   off += align256((size_t)(N + 1) * 4);
    int* cursor = (int*)(ws + off);   off += align256((size_t)N * 4);
    int* partials = (int*)(ws + off); off += 256;
    int* elist = (int*)(ws + off);    off += align256((size_t)E * 4);
    uint4* xsb = (uint4*)(ws + off);  off += align256((size_t)N * FDIM * 2);
    uint4* zb = (uint4*)(ws + off);   off += align256((size_t)N * FDIM * 2);
    uint4* Warr = (uint4*)(ws + off); off += align256((size_t)(FDIM / 8) * HDIM * 16);
    const bool fast = (ws_size >= off);

    const int nblk_scan1 = (N + SCAN_CHUNK - 1) / SCAN_CHUNK;

    k_zero<<<(N + 255) / 256, 256, 0, stream>>>(deg, N);
    k_count<<<(E + 255) / 256, 256, 0, stream>>>(dstp, deg, E);
    k_scan1<<<nblk_scan1, 256, 0, stream>>>(deg, rowptr, partials, dinv, N);
    k_scan2<<<1, 64, 0, stream>>>(partials, nblk_scan1);
    k_scan3<<<(N + 1 + 255) / 256, 256, 0, stream>>>(rowptr, partials, cursor, N, E);
    k_fill<<<(E + 255) / 256, 256, 0, stream>>>(srcp, dstp, cursor, elist, E);

    if (fast) {
        k_warr<<<((FDIM / 8) * HDIM + 255) / 256, 256, 0, stream>>>(W, Warr);
        const long long nchunks = (long long)N * (FDIM / 8);
        k_prescale<<<(int)((nchunks + 255) / 256), 256, 0, stream>>>(x, dinv, xsb, N);
        k_gather_bf16<<<(N + 15) / 16, 256, 0, stream>>>(xsb, dinv, rowptr, elist, zb, N);
        k_gemm_mfma<<<(N + 127) / 128, 128, 0, stream>>>(Warr, b,
                                                         (const unsigned short*)zb, out, N);
    } else {
        k_gather_f32<<<(N + 7) / 8, 256, 0, stream>>>(x, dinv, rowptr, elist, out, N);
        k_gemm_relu<<<512, 512, 0, stream>>>(W, b, out, N);
    }
}

// Round 5
// 92.630 us; speedup vs baseline: 12.3751x; 1.5259x over previous
//
#include <hip/hip_runtime.h>
#include <stdint.h>

// GCNConv forward on MI355X — aggregate-then-transform, bf16 MFMA, 6 launches.
//
//   out[t] = relu( ( dinv[t] * sum_{s in N(t) ∪ {t}} dinv[s] * x[s] ) @ W + b )
//
// Pipeline (fast path):
//   1. k_setup      : deg=0, pack W -> bf16 chunk-major Warr
//   2. k_count_slot : deg histogram; slot[i] = old count (CSR local slot)
//   3. k_scan1      : per-chunk exclusive scan of deg -> rowptr, + dinv
//   4. k_scan23     : add chunk offsets (redundant partial sum), rowptr[n]=e
//   5. k_fillpre    : elist[rowptr[d]+slot[i]] = src[i]  (no atomics)
//                     ∥ xsb = bf16(dinv*x)  (co-scheduled in same kernel)
//   6. k_gather_gemm: per block: gather 16 rows -> swizzled LDS tile,
//                     4 waves MFMA vs VGPR-resident W frags, relu+bias -> out

#define FDIM 128
#define HDIM 128
#define SCAN_CHUNK 1024

using s8v   = __attribute__((ext_vector_type(8))) short;  // 8 bf16 = 4 VGPR
using f32x4 = __attribute__((ext_vector_type(4))) float;  // MFMA C/D

__device__ __forceinline__ unsigned bf16rn(float f) {
    unsigned u = __float_as_uint(f);
    return (u + 0x7fffu + ((u >> 16) & 1u)) >> 16;  // RNE
}
__device__ __forceinline__ void upadd(unsigned w, float& lo, float& hi) {
    lo += __uint_as_float(w << 16);
    hi += __uint_as_float(w & 0xffff0000u);
}

// ---------------- 1. setup: zero deg + pack Warr ----------------
__global__ __launch_bounds__(256) void k_setup(int* __restrict__ deg,
                                               const float* __restrict__ W,
                                               uint4* __restrict__ Warr, int n) {
    const int i = blockIdx.x * 256 + threadIdx.x;
    if (i < n) deg[i] = 0;
    if (i < (FDIM / 8) * HDIM) {
        const int chunk = i >> 7, nn = i & 127;
        float v[8];
#pragma unroll
        for (int j = 0; j < 8; ++j) v[j] = W[(chunk * 8 + j) * HDIM + nn];
        uint4 o;
        o.x = bf16rn(v[0]) | (bf16rn(v[1]) << 16);
        o.y = bf16rn(v[2]) | (bf16rn(v[3]) << 16);
        o.z = bf16rn(v[4]) | (bf16rn(v[5]) << 16);
        o.w = bf16rn(v[6]) | (bf16rn(v[7]) << 16);
        Warr[i] = o;
    }
}

// ---------------- 2. degree histogram + local slot ----------------
__global__ __launch_bounds__(256) void k_count_slot(const int* __restrict__ dst,
                                                    int* __restrict__ deg,
                                                    int* __restrict__ slot, int e) {
    int i = blockIdx.x * 256 + threadIdx.x;
    if (i < e) slot[i] = atomicAdd(&deg[dst[i]], 1);
}

// ---------------- 3. scan (chunk-local) + dinv ----------------
__global__ __launch_bounds__(256) void k_scan1(const int* __restrict__ deg,
                                               int* __restrict__ rowptr,
                                               int* __restrict__ partials,
                                               float* __restrict__ dinv, int n) {
    __shared__ int sdata[256];
    const int tid = threadIdx.x;
    const int base = blockIdx.x * SCAN_CHUNK + tid * 4;
    int v[4];
    int s = 0;
#pragma unroll
    for (int j = 0; j < 4; ++j) {
        int idx = base + j;
        v[j] = (idx < n) ? deg[idx] : 0;
        if (idx < n) dinv[idx] = rsqrtf((float)v[j] + 1.0f);  // +1 self-loop
        s += v[j];
    }
    sdata[tid] = s;
    __syncthreads();
    for (int off = 1; off < 256; off <<= 1) {
        int t = (tid >= off) ? sdata[tid - off] : 0;
        __syncthreads();
        sdata[tid] += t;
        __syncthreads();
    }
    int run = sdata[tid] - s;
#pragma unroll
    for (int j = 0; j < 4; ++j) {
        int idx = base + j;
        if (idx < n) rowptr[idx] = run;
        run += v[j];
    }
    if (tid == 255) partials[blockIdx.x] = sdata[255];
}

// ---------------- 4. add chunk offsets ----------------
__global__ __launch_bounds__(256) void k_scan23(int* __restrict__ rowptr,
                                                const int* __restrict__ partials,
                                                int n, int e) {
    const int i = blockIdx.x * 256 + threadIdx.x;
    const int nb = blockIdx.x >> 2;  // = i >> 10, uniform per block
    int s = 0;
    for (int k = 0; k < nb; ++k) s += partials[k];  // uniform broadcast loads
    if (i < n) rowptr[i] += s;
    if (i == n) rowptr[n] = e;
}

// ---------------- 5. fill (no atomics) ∥ prescale ----------------
__global__ __launch_bounds__(256) void k_fillpre(const int* __restrict__ src,
                                                 const int* __restrict__ dst,
                                                 const int* __restrict__ slot,
                                                 const int* __restrict__ rowptr,
                                                 int* __restrict__ elist,
                                                 const float* __restrict__ x,
                                                 const float* __restrict__ dinv,
                                                 uint4* __restrict__ xsb,
                                                 int e, int n, int fillBlocks) {
    if ((int)blockIdx.x < fillBlocks) {
        const int i = blockIdx.x * 256 + threadIdx.x;
        if (i < e) {
            const int d = dst[i];
            elist[rowptr[d] + slot[i]] = src[i];
        }
    } else {
        const long long idx = (long long)(blockIdx.x - fillBlocks) * 256 + threadIdx.x;
        if (idx >= (long long)n * (FDIM / 8)) return;
        const int node = (int)(idx >> 4);
        const float di = dinv[node];
        const float4* xp = (const float4*)x + idx * 2;
        const float4 a = xp[0], b = xp[1];
        uint4 o;
        o.x = bf16rn(a.x * di) | (bf16rn(a.y * di) << 16);
        o.y = bf16rn(a.z * di) | (bf16rn(a.w * di) << 16);
        o.z = bf16rn(b.x * di) | (bf16rn(b.y * di) << 16);
        o.w = bf16rn(b.z * di) | (bf16rn(b.w * di) << 16);
        xsb[idx] = o;
    }
}

// ---------------- 6. fused gather + MFMA GEMM ----------------
// Block = 256 thr (4 waves) = 16 nodes. Gather phase: 16 lanes/node, unroll 4.
// LDS tile zlds[row][chunk ^ row] (XOR swizzle -> bank-optimal ds_read_b128).
// GEMM phase: wave w owns output cols [w*32, w*32+32); W frags in VGPRs.
__global__ __launch_bounds__(256) void k_gather_gemm(
    const uint4* __restrict__ xsb, const float* __restrict__ dinv,
    const int* __restrict__ rowptr, const int* __restrict__ elist,
    const uint4* __restrict__ Warr, const float* __restrict__ bias,
    float* __restrict__ out, int n) {
    __shared__ uint4 zlds[16][16];  // 4 KB
    const int tid = threadIdx.x;
    const int r = tid >> 4, q = tid & 15;
    const int node = blockIdx.x * 16 + r;
    const int wave = tid >> 6, lane = tid & 63;
    const int l16 = lane & 15, lg = lane >> 4;

    // Preload W fragments (L2-hot) + bias while gather runs.
    s8v wf[2][4];
#pragma unroll
    for (int ntl = 0; ntl < 2; ++ntl)
#pragma unroll
        for (int ks = 0; ks < 4; ++ks)
            wf[ntl][ks] = *(const s8v*)&Warr[(ks * 4 + lg) * 128 +
                                             (wave * 2 + ntl) * 16 + l16];
    float bv0 = bias[(wave * 2 + 0) * 16 + l16];
    float bv1 = bias[(wave * 2 + 1) * 16 + l16];

    if (node < n) {
        const uint4* xq = xsb + q;  // row stride = 16 uint4
        float a0, a1, a2, a3, a4, a5, a6, a7;
        {
            const uint4 v = xq[(size_t)node * 16];  // self term (pre-scaled)
            a0 = __uint_as_float(v.x << 16); a1 = __uint_as_float(v.x & 0xffff0000u);
            a2 = __uint_as_float(v.y << 16); a3 = __uint_as_float(v.y & 0xffff0000u);
            a4 = __uint_as_float(v.z << 16); a5 = __uint_as_float(v.z & 0xffff0000u);
            a6 = __uint_as_float(v.w << 16); a7 = __uint_as_float(v.w & 0xffff0000u);
        }
        int j = rowptr[node];
        const int end = rowptr[node + 1];
        for (; j + 3 < end; j += 4) {  // 4 outstanding row-gathers
            const int s0 = elist[j], s1 = elist[j + 1];
            const int s2 = elist[j + 2], s3 = elist[j + 3];
            const uint4 u0 = xq[(size_t)s0 * 16];
            const uint4 u1 = xq[(size_t)s1 * 16];
            const uint4 u2 = xq[(size_t)s2 * 16];
            const uint4 u3 = xq[(size_t)s3 * 16];
            upadd(u0.x, a0, a1); upadd(u0.y, a2, a3); upadd(u0.z, a4, a5); upadd(u0.w, a6, a7);
            upadd(u1.x, a0, a1); upadd(u1.y, a2, a3); upadd(u1.z, a4, a5); upadd(u1.w, a6, a7);
            upadd(u2.x, a0, a1); upadd(u2.y, a2, a3); upadd(u2.z, a4, a5); upadd(u2.w, a6, a7);
            upadd(u3.x, a0, a1); upadd(u3.y, a2, a3); upadd(u3.z, a4, a5); upadd(u3.w, a6, a7);
        }
        for (; j < end; ++j) {
            const uint4 u = xq[(size_t)elist[j] * 16];
            upadd(u.x, a0, a1); upadd(u.y, a2, a3); upadd(u.z, a4, a5); upadd(u.w, a6, a7);
        }
        const float di = dinv[node];
        uint4 o;
        o.x = bf16rn(a0 * di) | (bf16rn(a1 * di) << 16);
        o.y = bf16rn(a2 * di) | (bf16rn(a3 * di) << 16);
        o.z = bf16rn(a4 * di) | (bf16rn(a5 * di) << 16);
        o.w = bf16rn(a6 * di) | (bf16rn(a7 * di) << 16);
        zlds[r][q ^ r] = o;
    }
    __syncthreads();

    // A fragments from swizzled LDS tile.
    s8v afr[4];
#pragma unroll
    for (int ks = 0; ks < 4; ++ks)
        afr[ks] = *(const s8v*)&zlds[l16][(ks * 4 + lg) ^ l16];

#pragma unroll
    for (int ntl = 0; ntl < 2; ++ntl) {
        f32x4 acc = (f32x4){0.f, 0.f, 0.f, 0.f};
#pragma unroll
        for (int ks = 0; ks < 4; ++ks)
            acc = __builtin_amdgcn_mfma_f32_16x16x32_bf16(afr[ks], wf[ntl][ks], acc, 0, 0, 0);
        const int col = (wave * 2 + ntl) * 16 + l16;
        const float bv = ntl ? bv1 : bv0;
#pragma unroll
        for (int rr = 0; rr < 4; ++rr) {
            const int row = blockIdx.x * 16 + lg * 4 + rr;
            if (row < n) out[(size_t)row * HDIM + col] = fmaxf(acc[rr] + bv, 0.0f);
        }
    }
}

// ---------------- fallback path: fp32 ----------------
__global__ __launch_bounds__(256) void k_fill_simple(const int* __restrict__ src,
                                                     const int* __restrict__ dst,
                                                     const int* __restrict__ slot,
                                                     const int* __restrict__ rowptr,
                                                     int* __restrict__ elist, int e) {
    int i = blockIdx.x * 256 + threadIdx.x;
    if (i < e) elist[rowptr[dst[i]] + slot[i]] = src[i];
}

__global__ __launch_bounds__(256) void k_gather_f32(const float* __restrict__ x,
                                                    const float* __restrict__ dinv,
                                                    const int* __restrict__ rowptr,
                                                    const int* __restrict__ elist,
                                                    float* __restrict__ z, int n) {
    const int lane = threadIdx.x & 31;
    const int node = blockIdx.x * 8 + (threadIdx.x >> 5);
    if (node >= n) return;
    const float di = dinv[node];
    float4 v = ((const float4*)(x + (size_t)node * FDIM))[lane];
    float4 sum;
    sum.x = di * v.x; sum.y = di * v.y; sum.z = di * v.z; sum.w = di * v.w;
    const int beg = rowptr[node], end = rowptr[node + 1];
    for (int j = beg; j < end; ++j) {
        const int s = elist[j];
        const float ds = dinv[s];
        const float4 u = ((const float4*)(x + (size_t)s * FDIM))[lane];
        sum.x = fmaf(ds, u.x, sum.x);
        sum.y = fmaf(ds, u.y, sum.y);
        sum.z = fmaf(ds, u.z, sum.z);
        sum.w = fmaf(ds, u.w, sum.w);
    }
    float4 o;
    o.x = di * sum.x; o.y = di * sum.y; o.z = di * sum.z; o.w = di * sum.w;
    ((float4*)(z + (size_t)node * FDIM))[lane] = o;
}

__global__ __launch_bounds__(512) void k_gemm_relu(const float* __restrict__ W,
                                                   const float* __restrict__ bias,
                                                   float* __restrict__ zo, int n) {
    __shared__ float Wl[FDIM * HDIM];
    __shared__ float xs[4][FDIM];
    const int t = threadIdx.x;
    const int h = t & (HDIM - 1);
    const int g = t >> 7;
    {
        const float4* W4 = (const float4*)W;
        float4* Wl4 = (float4*)Wl;
        for (int i = t; i < FDIM * HDIM / 4; i += 512) Wl4[i] = W4[i];
    }
    __syncthreads();
    const float bv = bias[h];
    const int nq = (n + 3) >> 2;
    for (int q = blockIdx.x; q < nq; q += gridDim.x) {
        const int row = q * 4 + g;
        if (row < n) xs[g][h] = zo[(size_t)row * HDIM + h];
        __syncthreads();
        if (row < n) {
            float acc = bv;
#pragma unroll
            for (int k = 0; k < FDIM; ++k)
                acc = fmaf(xs[g][k], Wl[k * HDIM + h], acc);
            zo[(size_t)row * HDIM + h] = fmaxf(acc, 0.0f);
        }
        __syncthreads();
    }
}

extern "C" void kernel_launch(void* const* d_in, const int* in_sizes, int n_in,
                              void* d_out, int out_size, void* d_ws, size_t ws_size,
                              hipStream_t stream) {
    const float* x = (const float*)d_in[0];
    const float* W = (const float*)d_in[1];
    const float* b = (const float*)d_in[2];
    const int* ei = (const int*)d_in[3];
    float* out = (float*)d_out;

    const int H = in_sizes[2];      // 128
    const int F = in_sizes[1] / H;  // 128
    const int N = in_sizes[0] / F;  // 50000
    const int E = in_sizes[3] / 2;  // 600000
    const int* srcp = ei;
    const int* dstp = ei + E;

    auto align256 = [](size_t v) { return (v + 255) & ~(size_t)255; };
    char* ws = (char*)d_ws;
    size_t off = 0;
    int* deg = (int*)(ws + off);      off += align256((size_t)N * 4);
    float* dinv = (float*)(ws + off); off += align256((size_t)N * 4);
    int* rowptr = (int*)(ws + off);   off += align256((size_t)(N + 1) * 4);
    int* slot = (int*)(ws + off);     off += align256((size_t)E * 4);
    int* partials = (int*)(ws + off); off += 256;
    int* elist = (int*)(ws + off);    off += align256((size_t)E * 4);
    const size_t base_off = off;
    uint4* xsb = (uint4*)(ws + off);  off += align256((size_t)N * FDIM * 2);
    uint4* Warr = (uint4*)(ws + off); off += align256((size_t)(FDIM / 8) * HDIM * 16);
    const bool fast = (ws_size >= off);

    const int nblk_scan1 = (N + SCAN_CHUNK - 1) / SCAN_CHUNK;

    if (fast) {
        k_setup<<<(N + 255) / 256, 256, 0, stream>>>(deg, W, Warr, N);
        k_count_slot<<<(E + 255) / 256, 256, 0, stream>>>(dstp, deg, slot, E);
        k_scan1<<<nblk_scan1, 256, 0, stream>>>(deg, rowptr, partials, dinv, N);
        k_scan23<<<(N + 1 + 255) / 256, 256, 0, stream>>>(rowptr, partials, N, E);
        const int fillBlocks = (E + 255) / 256;
        const long long nchunks = (long long)N * (FDIM / 8);
        const int preBlocks = (int)((nchunks + 255) / 256);
        k_fillpre<<<fillBlocks + preBlocks, 256, 0, stream>>>(
            srcp, dstp, slot, rowptr, elist, x, dinv, xsb, E, N, fillBlocks);
        k_gather_gemm<<<(N + 15) / 16, 256, 0, stream>>>(xsb, dinv, rowptr, elist,
                                                         Warr, b, out, N);
    } else {
        k_setup<<<(N + 255) / 256, 256, 0, stream>>>(deg, W, (uint4*)(ws + base_off), N);
        k_count_slot<<<(E + 255) / 256, 256, 0, stream>>>(dstp, deg, slot, E);
        k_scan1<<<nblk_scan1, 256, 0, stream>>>(deg, rowptr, partials, dinv, N);
        k_scan23<<<(N + 1 + 255) / 256, 256, 0, stream>>>(rowptr, partials, N, E);
        k_fill_simple<<<(E + 255) / 256, 256, 0, stream>>>(srcp, dstp, slot, rowptr, elist, E);
        k_gather_f32<<<(N + 7) / 8, 256, 0, stream>>>(x, dinv, rowptr, elist, out, N);
        k_gemm_relu<<<512, 512, 0, stream>>>(W, b, out, N);
    }
}